// Round 1
// baseline (804.401 us; speedup 1.0000x reference)
//
#include <hip/hip_runtime.h>

#define NEGSLOPE 0.2f
#define NINF (-3.4e38f)

// ---------------------------------------------------------------------------
// prep: W1 (384,64) row-major  ->  w1t[o][j] = W1[j][o]   (o<64, j<384)
// so that for fixed summation channel o, the 384 weights are consecutive
// (perfect wave-uniform s_load stream in the mlp kernel).
// ---------------------------------------------------------------------------
__global__ void prep_w1t(const float* __restrict__ w1, float* __restrict__ w1t) {
    int i = blockIdx.x * 256 + threadIdx.x;
    if (i < 384 * 64) {
        int o = i / 384;
        int j = i - o * 384;
        w1t[i] = w1[j * 64 + o];
    }
}

// ---------------------------------------------------------------------------
// topk: for each row (b,n), indices of the 20 largest pd[j].
// pd[j] = 2*dot(x_n, x_j) - ||x_n||^2 - ||x_j||^2   (self gives exactly 0).
// One wave per row (4 rows sequentially). Lane holds j = t*64+lane, t<32.
// pd values live in a per-wave LDS strip; per-lane maxima cached in 4 groups
// of 8 so extraction only re-reads 8 values. Wave argmax via shfl_xor
// butterfly, tie-break = smaller j (matches jax.lax.top_k; ties are
// essentially impossible with random data anyway, and only the SET matters
// because of the max over k downstream).
// ---------------------------------------------------------------------------
__global__ __launch_bounds__(256) void topk_kernel(const float* __restrict__ x,
                                                   int* __restrict__ idx_out) {
    __shared__ float pdL[4][2048];
    const int wave = threadIdx.x >> 6;
    const int lane = threadIdx.x & 63;
    float* pd = pdL[wave];
    const int rowBase = blockIdx.x * 16 + wave * 4;

    for (int r = 0; r < 4; ++r) {
        const int row = rowBase + r;
        const int b = row >> 11;
        const int n = row & 2047;
        const float* xb = x + b * 6144;      // x[b][c][j] at xb[c*2048+j]
        const float xn0 = xb[n];
        const float xn1 = xb[2048 + n];
        const float xn2 = xb[4096 + n];
        const float xxn = xn0 * xn0 + xn1 * xn1 + xn2 * xn2;

        float gmax[4];
        int garg[4];
#pragma unroll
        for (int g = 0; g < 4; ++g) { gmax[g] = NINF; garg[g] = 0; }

#pragma unroll
        for (int t = 0; t < 32; ++t) {
            const int j = t * 64 + lane;
            const float c0 = xb[j];
            const float c1 = xb[2048 + j];
            const float c2 = xb[4096 + j];
            const float dot = c0 * xn0 + c1 * xn1 + c2 * xn2;
            const float xxj = c0 * c0 + c1 * c1 + c2 * c2;
            const float p = 2.f * dot - xxn - xxj;
            pd[j] = p;
            const int g = t >> 3;
            if (p > gmax[g]) { gmax[g] = p; garg[g] = j; }
        }

        const int out_base = row * 20;
        for (int k = 0; k < 20; ++k) {
            // lane-best of the 4 cached group maxima
            float bv = gmax[0];
            int bj = garg[0];
#pragma unroll
            for (int g = 1; g < 4; ++g) {
                if (gmax[g] > bv || (gmax[g] == bv && garg[g] < bj)) {
                    bv = gmax[g]; bj = garg[g];
                }
            }
            // wave argmax butterfly (64 lanes)
#pragma unroll
            for (int s = 32; s >= 1; s >>= 1) {
                const float ov = __shfl_xor(bv, s, 64);
                const int oj = __shfl_xor(bj, s, 64);
                if (ov > bv || (ov == bv && oj < bj)) { bv = ov; bj = oj; }
            }
            if (lane == 0) idx_out[out_base + k] = bj;

            // zap winner, recompute its group's cached max (uniform group id)
            const int wl = bj & 63;
            const int wt = bj >> 6;
            const int wg = wt >> 3;
            if (lane == wl) pd[bj] = NINF;
            float ng = NINF;
            int na = 0;
#pragma unroll
            for (int u = 0; u < 8; ++u) {
                const int j = (wg * 8 + u) * 64 + lane;
                const float p = pd[j];
                if (p > ng) { ng = p; na = j; }
            }
#pragma unroll
            for (int g = 0; g < 4; ++g) {
                if (g == wg) { gmax[g] = ng; garg[g] = na; }
            }
        }
    }
}

// ---------------------------------------------------------------------------
// mlp: per point n -- gather 20 neighbors, edge MLP, bilinear W1 stage,
// bn+leaky, max over k, final 64->3 head, write (B,3,N).
// Mapping: lane <-> n (64 points per block), 10 waves each own 2 k's.
// All weights are wave-uniform -> scalar loads feeding v_fma's SGPR slot;
// hot loop is ~pure fp32 FMA. acc[64] + x1[64] live in VGPRs (static
// indices only; o-loop kept rolled to protect I-cache).
// ---------------------------------------------------------------------------
__global__ __launch_bounds__(640) void mlp_kernel(
    const float* __restrict__ x, const int* __restrict__ idx,
    const float* __restrict__ w0, const float* __restrict__ bn0s,
    const float* __restrict__ bn0b, const float* __restrict__ w1t,
    const float* __restrict__ bn1s, const float* __restrict__ bn1b,
    const float* __restrict__ wc, const float* __restrict__ bncs,
    const float* __restrict__ bncb, float* __restrict__ out) {
    __shared__ float ldsX1[64][65];
    const int wave = threadIdx.x >> 6;   // 0..9
    const int lane = threadIdx.x & 63;
    const int b = blockIdx.x >> 5;       // 8 batches x 32 n-groups
    const int n0 = (blockIdx.x & 31) * 64;
    const int n = n0 + lane;
    const float* xb = x + b * 6144;
    const float xn0 = xb[n];
    const float xn1 = xb[2048 + n];
    const float xn2 = xb[4096 + n];
    const int row = (b << 11) + n;

    float x1[64];
#pragma unroll
    for (int u = 0; u < 64; ++u) x1[u] = NINF;

    for (int kk = 0; kk < 2; ++kk) {
        const int k = wave * 2 + kk;
        const int j = idx[row * 20 + k];
        const float e0 = xb[j] - xn0;
        const float e1 = xb[2048 + j] - xn1;
        const float e2 = xb[4096 + j] - xn2;
        // e = [e0, e1, e2, xn0, xn1, xn2]

        float acc[64];
#pragma unroll
        for (int u = 0; u < 64; ++u) acc[u] = 0.f;

#pragma unroll 1
        for (int o = 0; o < 64; ++o) {
            const float* w0r = w0 + o * 6;
            float yo = w0r[0] * e0 + w0r[1] * e1 + w0r[2] * e2 +
                       w0r[3] * xn0 + w0r[4] * xn1 + w0r[5] * xn2;
            yo = yo * bn0s[o] + bn0b[o];
            yo = fmaxf(yo, NEGSLOPE * yo);   // leaky
            const float* wt = w1t + o * 384;
#pragma unroll
            for (int u = 0; u < 64; ++u) {
                const float* wtu = wt + u * 6;
                const float t = wtu[0] * e0 + wtu[1] * e1 + wtu[2] * e2 +
                                wtu[3] * xn0 + wtu[4] * xn1 + wtu[5] * xn2;
                acc[u] += yo * t;
            }
        }

#pragma unroll
        for (int u = 0; u < 64; ++u) {
            float v = acc[u] * bn1s[u] + bn1b[u];
            v = fmaxf(v, NEGSLOPE * v);      // leaky
            x1[u] = fmaxf(x1[u], v);
        }
    }

    // merge running maxima across the 10 waves (disjoint k subsets)
    for (int t = threadIdx.x; t < 64 * 65; t += 640) ((float*)ldsX1)[t] = NINF;
    __syncthreads();
    for (int w = 0; w < 10; ++w) {
        if (wave == w) {
#pragma unroll
            for (int u = 0; u < 64; ++u)
                ldsX1[lane][u] = fmaxf(ldsX1[lane][u], x1[u]);
        }
        __syncthreads();
    }

    if (wave == 0) {
        float z[3];
#pragma unroll
        for (int c = 0; c < 3; ++c) {
            float s = 0.f;
#pragma unroll
            for (int u = 0; u < 64; ++u) s += ldsX1[lane][u] * wc[c * 64 + u];
            s = s * bncs[c] + bncb[c];
            z[c] = fmaxf(s, NEGSLOPE * s);   // leaky
        }
#pragma unroll
        for (int c = 0; c < 3; ++c)
            out[(b * 3 + c) * 2048 + n0 + lane] = z[c];
    }
}

// ---------------------------------------------------------------------------
extern "C" void kernel_launch(void* const* d_in, const int* in_sizes, int n_in,
                              void* d_out, int out_size, void* d_ws, size_t ws_size,
                              hipStream_t stream) {
    const float* x    = (const float*)d_in[0];
    const float* W0   = (const float*)d_in[1];
    const float* bn0s = (const float*)d_in[2];
    const float* bn0b = (const float*)d_in[3];
    const float* W1   = (const float*)d_in[4];
    const float* bn1s = (const float*)d_in[5];
    const float* bn1b = (const float*)d_in[6];
    const float* Wc   = (const float*)d_in[7];
    const float* bncs = (const float*)d_in[8];
    const float* bncb = (const float*)d_in[9];

    float* w1t = (float*)d_ws;                       // 24576 floats = 96 KiB
    int* idx = (int*)((char*)d_ws + 131072);         // 16384*20 ints = 1.25 MiB

    prep_w1t<<<96, 256, 0, stream>>>(W1, w1t);
    topk_kernel<<<1024, 256, 0, stream>>>(x, idx);
    mlp_kernel<<<256, 640, 0, stream>>>(x, idx, W0, bn0s, bn0b, w1t,
                                        bn1s, bn1b, Wc, bncs, bncb,
                                        (float*)d_out);
}

// Round 2
// 283.825 us; speedup vs baseline: 2.8341x; 2.8341x over previous
//
#include <hip/hip_runtime.h>

#define NEGSLOPE 0.2f
#define NINF (-3.4e38f)

typedef _Float16 half8 __attribute__((ext_vector_type(8)));
typedef float f32x4 __attribute__((ext_vector_type(4)));

#define YSTRIDE 72  // f16 units, padded from 64 to break bank alignment

// ---------------------------------------------------------------------------
// prep: W1 (384,64) row-major -> per-lane f16 B-fragment order.
// Fragment (ks,t): lane L (q=L>>4, c=L&15) holds 8 f16:
//   B[o = ks*32 + q*8 + j][p' = 16t + c],  p' = i*64+u,  W1'[o][p'] = W1[u*6+i][o]
// ---------------------------------------------------------------------------
__global__ void prep_w1f(const float* __restrict__ w1, _Float16* __restrict__ w1f) {
    int tid = blockIdx.x * 256 + threadIdx.x;
    if (tid < 24576) {
        int j = tid & 7;
        int L = (tid >> 3) & 63;
        int rest = tid >> 9;          // = ks*24 + t
        int t = rest % 24;
        int ks = rest / 24;
        int q = L >> 4, c = L & 15;
        int p = 16 * t + c;
        int u = p & 63, i = p >> 6;
        int o = ks * 32 + q * 8 + j;
        w1f[tid] = (_Float16)w1[(u * 6 + i) * 64 + o];
    }
}

// ---------------------------------------------------------------------------
// topk (unchanged from R1, known-correct): indices of 20 largest pd per row.
// ---------------------------------------------------------------------------
__global__ __launch_bounds__(256) void topk_kernel(const float* __restrict__ x,
                                                   int* __restrict__ idx_out) {
    __shared__ float pdL[4][2048];
    const int wave = threadIdx.x >> 6;
    const int lane = threadIdx.x & 63;
    float* pd = pdL[wave];
    const int rowBase = blockIdx.x * 16 + wave * 4;

    for (int r = 0; r < 4; ++r) {
        const int row = rowBase + r;
        const int b = row >> 11;
        const int n = row & 2047;
        const float* xb = x + b * 6144;
        const float xn0 = xb[n];
        const float xn1 = xb[2048 + n];
        const float xn2 = xb[4096 + n];
        const float xxn = xn0 * xn0 + xn1 * xn1 + xn2 * xn2;

        float gmax[4];
        int garg[4];
#pragma unroll
        for (int g = 0; g < 4; ++g) { gmax[g] = NINF; garg[g] = 0; }

#pragma unroll
        for (int t = 0; t < 32; ++t) {
            const int j = t * 64 + lane;
            const float c0 = xb[j];
            const float c1 = xb[2048 + j];
            const float c2 = xb[4096 + j];
            const float dot = c0 * xn0 + c1 * xn1 + c2 * xn2;
            const float xxj = c0 * c0 + c1 * c1 + c2 * c2;
            const float p = 2.f * dot - xxn - xxj;
            pd[j] = p;
            const int g = t >> 3;
            if (p > gmax[g]) { gmax[g] = p; garg[g] = j; }
        }

        const int out_base = row * 20;
        for (int k = 0; k < 20; ++k) {
            float bv = gmax[0];
            int bj = garg[0];
#pragma unroll
            for (int g = 1; g < 4; ++g) {
                if (gmax[g] > bv || (gmax[g] == bv && garg[g] < bj)) {
                    bv = gmax[g]; bj = garg[g];
                }
            }
#pragma unroll
            for (int s = 32; s >= 1; s >>= 1) {
                const float ov = __shfl_xor(bv, s, 64);
                const int oj = __shfl_xor(bj, s, 64);
                if (ov > bv || (ov == bv && oj < bj)) { bv = ov; bj = oj; }
            }
            if (lane == 0) idx_out[out_base + k] = bj;

            const int wl = bj & 63;
            const int wt = bj >> 6;
            const int wg = wt >> 3;
            if (lane == wl) pd[bj] = NINF;
            float ng = NINF;
            int na = 0;
#pragma unroll
            for (int u = 0; u < 8; ++u) {
                const int j = (wg * 8 + u) * 64 + lane;
                const float p = pd[j];
                if (p > ng) { ng = p; na = j; }
            }
#pragma unroll
            for (int g = 0; g < 4; ++g) {
                if (g == wg) { gmax[g] = ng; garg[g] = na; }
            }
        }
    }
}

// ---------------------------------------------------------------------------
// mlp via MFMA: wave owns 4 points x 20 k = 80 edges (edge_local = k*4+pt),
// 5 M-tiles of 16. H = Y(16x64,f16) @ W1'(64x384,f16) per tile via
// mfma_f32_16x16x32_f16 (2 k-steps). Epilogue per n-tile t: i=t>>2,
// u=(t&3)*16+c, acc[edge][u] += C*e_i[edge]; then bn1+leaky, max over
// k (m in-reg, q via shfl), 64->3 head with c-lane reduction.
// ---------------------------------------------------------------------------
__global__ __launch_bounds__(128) void mlp_mfma(
    const float* __restrict__ x, const int* __restrict__ idx,
    const float* __restrict__ w0, const float* __restrict__ bn0s,
    const float* __restrict__ bn0b, const _Float16* __restrict__ w1f,
    const float* __restrict__ bn1s, const float* __restrict__ bn1b,
    const float* __restrict__ wc, const float* __restrict__ bncs,
    const float* __restrict__ bncb, float* __restrict__ out) {
    __shared__ __align__(16) _Float16 yL[2][80 * YSTRIDE];
    __shared__ __align__(16) float eL[2][6][80];
    const int wave = threadIdx.x >> 6;
    const int lane = threadIdx.x & 63;
    const int q = lane >> 4, c = lane & 15;
    const int gw = blockIdx.x * 2 + wave;     // 0..4095
    const int b = gw >> 9;                    // 512 waves per batch
    const int P0 = (gw & 511) * 4;
    const float* xb = x + b * 6144;
    _Float16* yw = yL[wave];
    float(*ew)[80] = eL[wave];

    // ---- e-stage: lane <-> edge_local (and +64 for lanes<16) ----
    float e0[6], e1_[6];
    {
        const int k = lane >> 2, pt = lane & 3;
        const int n = P0 + pt;
        const int j = idx[(b * 2048 + n) * 20 + k];
        const float c0 = xb[n], c1 = xb[2048 + n], c2 = xb[4096 + n];
        e0[0] = xb[j] - c0; e0[1] = xb[2048 + j] - c1; e0[2] = xb[4096 + j] - c2;
        e0[3] = c0; e0[4] = c1; e0[5] = c2;
#pragma unroll
        for (int i = 0; i < 6; ++i) ew[i][lane] = e0[i];
    }
#pragma unroll
    for (int i = 0; i < 6; ++i) e1_[i] = 0.f;
    if (lane < 16) {
        const int el = 64 + lane;
        const int k = el >> 2, pt = el & 3;
        const int n = P0 + pt;
        const int j = idx[(b * 2048 + n) * 20 + k];
        const float c0 = xb[n], c1 = xb[2048 + n], c2 = xb[4096 + n];
        e1_[0] = xb[j] - c0; e1_[1] = xb[2048 + j] - c1; e1_[2] = xb[4096 + j] - c2;
        e1_[3] = c0; e1_[4] = c1; e1_[5] = c2;
#pragma unroll
        for (int i = 0; i < 6; ++i) ew[i][el] = e1_[i];
    }

    // ---- y-stage: lane = edge, loop o; W0/bn0 are wave-uniform scalars ----
#pragma unroll 8
    for (int o = 0; o < 64; ++o) {
        const float s0 = bn0s[o], b0 = bn0b[o];
        const float* wr = w0 + o * 6;
        float y = wr[0] * e0[0] + wr[1] * e0[1] + wr[2] * e0[2] +
                  wr[3] * e0[3] + wr[4] * e0[4] + wr[5] * e0[5];
        y = y * s0 + b0;
        y = fmaxf(y, NEGSLOPE * y);
        yw[lane * YSTRIDE + o] = (_Float16)y;
        if (lane < 16) {
            float y2 = wr[0] * e1_[0] + wr[1] * e1_[1] + wr[2] * e1_[2] +
                       wr[3] * e1_[3] + wr[4] * e1_[4] + wr[5] * e1_[5];
            y2 = y2 * s0 + b0;
            y2 = fmaxf(y2, NEGSLOPE * y2);
            yw[(64 + lane) * YSTRIDE + o] = (_Float16)y2;
        }
    }

    __syncthreads();  // yL/eL cross-lane visibility

    // ---- A-fragments: A[m][ks], lane holds y[edge=16m+c][o=32ks+8q+j] ----
    half8 A[5][2];
#pragma unroll
    for (int m = 0; m < 5; ++m)
#pragma unroll
        for (int ks = 0; ks < 2; ++ks)
            A[m][ks] = *(const half8*)&yw[(16 * m + c) * YSTRIDE + 32 * ks + 8 * q];

    const half8* w1f8 = (const half8*)w1f;
    float bs1[4], bb1[4];
#pragma unroll
    for (int us = 0; us < 4; ++us) {
        bs1[us] = bn1s[16 * us + c];
        bb1[us] = bn1b[16 * us + c];
    }

    float acc[5][4][4];  // [m][reg r][us]
#pragma unroll
    for (int m = 0; m < 5; ++m)
#pragma unroll
        for (int r = 0; r < 4; ++r)
#pragma unroll
            for (int us = 0; us < 4; ++us) acc[m][r][us] = 0.f;

    // ---- main loop over 24 n-tiles ----
#pragma unroll
    for (int t = 0; t < 24; ++t) {
        const half8 Bf0 = w1f8[t * 64 + lane];
        const half8 Bf1 = w1f8[(24 + t) * 64 + lane];
        const int i = t >> 2;
        const int us = t & 3;
#pragma unroll
        for (int m = 0; m < 5; ++m) {
            f32x4 C = {0.f, 0.f, 0.f, 0.f};
            C = __builtin_amdgcn_mfma_f32_16x16x32_f16(A[m][0], Bf0, C, 0, 0, 0);
            C = __builtin_amdgcn_mfma_f32_16x16x32_f16(A[m][1], Bf1, C, 0, 0, 0);
            const f32x4 ev = *(const f32x4*)&ew[i][16 * m + 4 * q];
            acc[m][0][us] += C[0] * ev[0];
            acc[m][1][us] += C[1] * ev[1];
            acc[m][2][us] += C[2] * ev[2];
            acc[m][3][us] += C[3] * ev[3];
        }
    }

    // ---- bn1 + leaky + max over k (k = 4m+q) ----
    float x1[4][4];  // [pt r][us], u = 16*us + c
#pragma unroll
    for (int r = 0; r < 4; ++r)
#pragma unroll
        for (int us = 0; us < 4; ++us) {
            float v = NINF;
#pragma unroll
            for (int m = 0; m < 5; ++m) {
                float w = acc[m][r][us] * bs1[us] + bb1[us];
                w = fmaxf(w, NEGSLOPE * w);
                v = fmaxf(v, w);
            }
            // reduce over q (lanes ^16, ^32)
            v = fmaxf(v, __shfl_xor(v, 16, 64));
            v = fmaxf(v, __shfl_xor(v, 32, 64));
            x1[r][us] = v;
        }

    // ---- head: z[pt][co] = leaky(bnc(sum_u x1*wc)) ----
    float wcv[3][4];
#pragma unroll
    for (int co = 0; co < 3; ++co)
#pragma unroll
        for (int us = 0; us < 4; ++us) wcv[co][us] = wc[co * 64 + 16 * us + c];

    float part[4][3];
#pragma unroll
    for (int r = 0; r < 4; ++r)
#pragma unroll
        for (int co = 0; co < 3; ++co) {
            float s = x1[r][0] * wcv[co][0] + x1[r][1] * wcv[co][1] +
                      x1[r][2] * wcv[co][2] + x1[r][3] * wcv[co][3];
#pragma unroll
            for (int d = 1; d < 16; d <<= 1) s += __shfl_xor(s, d, 64);
            part[r][co] = s;
        }

    if (c == 0 && q < 3) {
        const float sc = bncs[q], bc = bncb[q];
#pragma unroll
        for (int r = 0; r < 4; ++r) {
            float z = part[r][q] * sc + bc;
            z = fmaxf(z, NEGSLOPE * z);
            out[(b * 3 + q) * 2048 + P0 + r] = z;
        }
    }
}

// ---------------------------------------------------------------------------
extern "C" void kernel_launch(void* const* d_in, const int* in_sizes, int n_in,
                              void* d_out, int out_size, void* d_ws, size_t ws_size,
                              hipStream_t stream) {
    const float* x    = (const float*)d_in[0];
    const float* W0   = (const float*)d_in[1];
    const float* bn0s = (const float*)d_in[2];
    const float* bn0b = (const float*)d_in[3];
    const float* W1   = (const float*)d_in[4];
    const float* bn1s = (const float*)d_in[5];
    const float* bn1b = (const float*)d_in[6];
    const float* Wc   = (const float*)d_in[7];
    const float* bncs = (const float*)d_in[8];
    const float* bncb = (const float*)d_in[9];

    _Float16* w1f = (_Float16*)d_ws;             // 24576 f16 = 48 KiB
    int* idx = (int*)((char*)d_ws + 65536);      // 16384*20 ints = 1.25 MiB

    prep_w1f<<<96, 256, 0, stream>>>(W1, w1f);
    topk_kernel<<<1024, 256, 0, stream>>>(x, idx);
    mlp_mfma<<<2048, 128, 0, stream>>>(x, idx, W0, bn0s, bn0b, w1f,
                                       bn1s, bn1b, Wc, bncs, bncb,
                                       (float*)d_out);
}

// Round 3
// 229.826 us; speedup vs baseline: 3.5000x; 1.2350x over previous
//
#include <hip/hip_runtime.h>

#define NEGSLOPE 0.2f
#define NINF (-3.4e38f)

typedef _Float16 half8 __attribute__((ext_vector_type(8)));
typedef float f32x4 __attribute__((ext_vector_type(4)));

#define YSTRIDE 72  // f16 units, padded from 64 to break bank alignment

// ---------------------------------------------------------------------------
// prep: W1 (384,64) row-major -> per-lane f16 B-fragment order. (unchanged)
// ---------------------------------------------------------------------------
__global__ void prep_w1f(const float* __restrict__ w1, _Float16* __restrict__ w1f) {
    int tid = blockIdx.x * 256 + threadIdx.x;
    if (tid < 24576) {
        int j = tid & 7;
        int L = (tid >> 3) & 63;
        int rest = tid >> 9;          // = ks*24 + t
        int t = rest % 24;
        int ks = rest / 24;
        int q = L >> 4, c = L & 15;
        int p = 16 * t + c;
        int u = p & 63, i = p >> 6;
        int o = ks * 32 + q * 8 + j;
        w1f[tid] = (_Float16)w1[(u * 6 + i) * 64 + o];
    }
}

// ---------------------------------------------------------------------------
// topk v2: one wave per row. Candidate t*64+lane (t<32). Sortable keys kept
// in VGPRs (sk[32], static indexing); zapped candidates tracked by a 32-bit
// per-lane mask. Wave argmax = 4-group lane-best (registers) + 6-step DPP
// reduction (row_shr 1/2/4/8, row_bcast 15/31) on (key, ~j) pairs — no LDS
// anywhere. Tiebreak: equal key -> larger ~j == smaller j (matches
// jax.lax.top_k; and only the SET matters downstream anyway).
// ---------------------------------------------------------------------------
__device__ __forceinline__ unsigned sortkey(float f) {
    unsigned u = __float_as_uint(f);
    return (u & 0x80000000u) ? ~u : (u | 0x80000000u);
}

template <int CTRL>
__device__ __forceinline__ void dpp_max_step(unsigned& k, unsigned& p) {
    unsigned ok = (unsigned)__builtin_amdgcn_update_dpp(0, (int)k, CTRL, 0xF, 0xF, false);
    unsigned op = (unsigned)__builtin_amdgcn_update_dpp(0, (int)p, CTRL, 0xF, 0xF, false);
    if (ok > k || (ok == k && op > p)) { k = ok; p = op; }
}

__global__ __launch_bounds__(256) void topk_kernel(const float* __restrict__ x,
                                                   int* __restrict__ idx_out) {
    const int wave = threadIdx.x >> 6;
    const int lane = threadIdx.x & 63;
    const int row = blockIdx.x * 4 + wave;
    const int b = row >> 11;
    const int n = row & 2047;
    const float* xb = x + b * 6144;
    const float xn0 = xb[n];
    const float xn1 = xb[2048 + n];
    const float xn2 = xb[4096 + n];
    const float xxn = xn0 * xn0 + xn1 * xn1 + xn2 * xn2;

    unsigned sk[32];       // sortable keys, one candidate per t (j = t*64+lane)
    unsigned gk[4], gp[4]; // per-group best (key, ~j)
#pragma unroll
    for (int g = 0; g < 4; ++g) { gk[g] = 0u; gp[g] = 0u; }

#pragma unroll
    for (int t = 0; t < 32; ++t) {
        const int j = t * 64 + lane;
        const float c0 = xb[j];
        const float c1 = xb[2048 + j];
        const float c2 = xb[4096 + j];
        const float dot = c0 * xn0 + c1 * xn1 + c2 * xn2;
        const float xxj = c0 * c0 + c1 * c1 + c2 * c2;
        const float p = 2.f * dot - xxn - xxj;
        const unsigned s = sortkey(p);
        sk[t] = s;
        const unsigned pj = ~(unsigned)j;
        const int g = t >> 3;
        if (s > gk[g] || (s == gk[g] && pj > gp[g])) { gk[g] = s; gp[g] = pj; }
    }

    unsigned zmask = 0u;
    const int out_base = row * 20;

#define RECOMP_STEP(T)                                                     \
    {                                                                      \
        const unsigned sv = ((zmask >> (T)) & 1u) ? 0u : sk[(T)];          \
        const unsigned pv = ~(unsigned)((T)*64 + lane);                    \
        if (sv > nk || (sv == nk && pv > np)) { nk = sv; np = pv; }        \
    }
#define RECOMP_GROUP(G)                                                    \
    {                                                                      \
        RECOMP_STEP((G)*8 + 0) RECOMP_STEP((G)*8 + 1) RECOMP_STEP((G)*8 + 2) \
        RECOMP_STEP((G)*8 + 3) RECOMP_STEP((G)*8 + 4) RECOMP_STEP((G)*8 + 5) \
        RECOMP_STEP((G)*8 + 6) RECOMP_STEP((G)*8 + 7)                      \
        gk[(G)] = nk; gp[(G)] = np;                                        \
    }

    for (int k = 0; k < 20; ++k) {
        // lane-best over the 4 cached group maxima
        unsigned bk = gk[0], bp = gp[0];
#pragma unroll
        for (int g = 1; g < 4; ++g) {
            if (gk[g] > bk || (gk[g] == bk && gp[g] > bp)) { bk = gk[g]; bp = gp[g]; }
        }
        // wave argmax: DPP reduction, result lands in lane 63
        dpp_max_step<0x111>(bk, bp);  // row_shr:1
        dpp_max_step<0x112>(bk, bp);  // row_shr:2
        dpp_max_step<0x114>(bk, bp);  // row_shr:4
        dpp_max_step<0x118>(bk, bp);  // row_shr:8
        dpp_max_step<0x142>(bk, bp);  // row_bcast:15
        dpp_max_step<0x143>(bk, bp);  // row_bcast:31
        const unsigned wp = (unsigned)__builtin_amdgcn_readlane((int)bp, 63);
        const unsigned bj = ~wp;      // winning candidate index (wave-uniform)
        if (lane == 0) idx_out[out_base + k] = (int)bj;

        if (k < 19) {
            const unsigned wt = bj >> 6;
            if (lane == (int)(bj & 63u)) zmask |= (1u << wt);
            const int wg = (int)(bj >> 9);
            unsigned nk = 0u, np = 0u;
            switch (wg) {
                case 0: RECOMP_GROUP(0) break;
                case 1: RECOMP_GROUP(1) break;
                case 2: RECOMP_GROUP(2) break;
                default: RECOMP_GROUP(3) break;
            }
        }
    }
#undef RECOMP_GROUP
#undef RECOMP_STEP
}

// ---------------------------------------------------------------------------
// mlp via MFMA (unchanged from R2, known-correct).
// ---------------------------------------------------------------------------
__global__ __launch_bounds__(128) void mlp_mfma(
    const float* __restrict__ x, const int* __restrict__ idx,
    const float* __restrict__ w0, const float* __restrict__ bn0s,
    const float* __restrict__ bn0b, const _Float16* __restrict__ w1f,
    const float* __restrict__ bn1s, const float* __restrict__ bn1b,
    const float* __restrict__ wc, const float* __restrict__ bncs,
    const float* __restrict__ bncb, float* __restrict__ out) {
    __shared__ __align__(16) _Float16 yL[2][80 * YSTRIDE];
    __shared__ __align__(16) float eL[2][6][80];
    const int wave = threadIdx.x >> 6;
    const int lane = threadIdx.x & 63;
    const int q = lane >> 4, c = lane & 15;
    const int gw = blockIdx.x * 2 + wave;     // 0..4095
    const int b = gw >> 9;                    // 512 waves per batch
    const int P0 = (gw & 511) * 4;
    const float* xb = x + b * 6144;
    _Float16* yw = yL[wave];
    float(*ew)[80] = eL[wave];

    float e0[6], e1_[6];
    {
        const int k = lane >> 2, pt = lane & 3;
        const int n = P0 + pt;
        const int j = idx[(b * 2048 + n) * 20 + k];
        const float c0 = xb[n], c1 = xb[2048 + n], c2 = xb[4096 + n];
        e0[0] = xb[j] - c0; e0[1] = xb[2048 + j] - c1; e0[2] = xb[4096 + j] - c2;
        e0[3] = c0; e0[4] = c1; e0[5] = c2;
#pragma unroll
        for (int i = 0; i < 6; ++i) ew[i][lane] = e0[i];
    }
#pragma unroll
    for (int i = 0; i < 6; ++i) e1_[i] = 0.f;
    if (lane < 16) {
        const int el = 64 + lane;
        const int k = el >> 2, pt = el & 3;
        const int n = P0 + pt;
        const int j = idx[(b * 2048 + n) * 20 + k];
        const float c0 = xb[n], c1 = xb[2048 + n], c2 = xb[4096 + n];
        e1_[0] = xb[j] - c0; e1_[1] = xb[2048 + j] - c1; e1_[2] = xb[4096 + j] - c2;
        e1_[3] = c0; e1_[4] = c1; e1_[5] = c2;
#pragma unroll
        for (int i = 0; i < 6; ++i) ew[i][el] = e1_[i];
    }

#pragma unroll 8
    for (int o = 0; o < 64; ++o) {
        const float s0 = bn0s[o], b0 = bn0b[o];
        const float* wr = w0 + o * 6;
        float y = wr[0] * e0[0] + wr[1] * e0[1] + wr[2] * e0[2] +
                  wr[3] * e0[3] + wr[4] * e0[4] + wr[5] * e0[5];
        y = y * s0 + b0;
        y = fmaxf(y, NEGSLOPE * y);
        yw[lane * YSTRIDE + o] = (_Float16)y;
        if (lane < 16) {
            float y2 = wr[0] * e1_[0] + wr[1] * e1_[1] + wr[2] * e1_[2] +
                       wr[3] * e1_[3] + wr[4] * e1_[4] + wr[5] * e1_[5];
            y2 = y2 * s0 + b0;
            y2 = fmaxf(y2, NEGSLOPE * y2);
            yw[(64 + lane) * YSTRIDE + o] = (_Float16)y2;
        }
    }

    __syncthreads();

    half8 A[5][2];
#pragma unroll
    for (int m = 0; m < 5; ++m)
#pragma unroll
        for (int ks = 0; ks < 2; ++ks)
            A[m][ks] = *(const half8*)&yw[(16 * m + c) * YSTRIDE + 32 * ks + 8 * q];

    const half8* w1f8 = (const half8*)w1f;
    float bs1[4], bb1[4];
#pragma unroll
    for (int us = 0; us < 4; ++us) {
        bs1[us] = bn1s[16 * us + c];
        bb1[us] = bn1b[16 * us + c];
    }

    float acc[5][4][4];
#pragma unroll
    for (int m = 0; m < 5; ++m)
#pragma unroll
        for (int r = 0; r < 4; ++r)
#pragma unroll
            for (int us = 0; us < 4; ++us) acc[m][r][us] = 0.f;

#pragma unroll
    for (int t = 0; t < 24; ++t) {
        const half8 Bf0 = w1f8[t * 64 + lane];
        const half8 Bf1 = w1f8[(24 + t) * 64 + lane];
        const int i = t >> 2;
        const int us = t & 3;
#pragma unroll
        for (int m = 0; m < 5; ++m) {
            f32x4 C = {0.f, 0.f, 0.f, 0.f};
            C = __builtin_amdgcn_mfma_f32_16x16x32_f16(A[m][0], Bf0, C, 0, 0, 0);
            C = __builtin_amdgcn_mfma_f32_16x16x32_f16(A[m][1], Bf1, C, 0, 0, 0);
            const f32x4 ev = *(const f32x4*)&ew[i][16 * m + 4 * q];
            acc[m][0][us] += C[0] * ev[0];
            acc[m][1][us] += C[1] * ev[1];
            acc[m][2][us] += C[2] * ev[2];
            acc[m][3][us] += C[3] * ev[3];
        }
    }

    float x1[4][4];
#pragma unroll
    for (int r = 0; r < 4; ++r)
#pragma unroll
        for (int us = 0; us < 4; ++us) {
            float v = NINF;
#pragma unroll
            for (int m = 0; m < 5; ++m) {
                float w = acc[m][r][us] * bs1[us] + bb1[us];
                w = fmaxf(w, NEGSLOPE * w);
                v = fmaxf(v, w);
            }
            v = fmaxf(v, __shfl_xor(v, 16, 64));
            v = fmaxf(v, __shfl_xor(v, 32, 64));
            x1[r][us] = v;
        }

    float wcv[3][4];
#pragma unroll
    for (int co = 0; co < 3; ++co)
#pragma unroll
        for (int us = 0; us < 4; ++us) wcv[co][us] = wc[co * 64 + 16 * us + c];

    float part[4][3];
#pragma unroll
    for (int r = 0; r < 4; ++r)
#pragma unroll
        for (int co = 0; co < 3; ++co) {
            float s = x1[r][0] * wcv[co][0] + x1[r][1] * wcv[co][1] +
                      x1[r][2] * wcv[co][2] + x1[r][3] * wcv[co][3];
#pragma unroll
            for (int d = 1; d < 16; d <<= 1) s += __shfl_xor(s, d, 64);
            part[r][co] = s;
        }

    if (c == 0 && q < 3) {
        const float sc = bncs[q], bc = bncb[q];
#pragma unroll
        for (int r = 0; r < 4; ++r) {
            float z = part[r][q] * sc + bc;
            z = fmaxf(z, NEGSLOPE * z);
            out[(b * 3 + q) * 2048 + P0 + r] = z;
        }
    }
}

// ---------------------------------------------------------------------------
extern "C" void kernel_launch(void* const* d_in, const int* in_sizes, int n_in,
                              void* d_out, int out_size, void* d_ws, size_t ws_size,
                              hipStream_t stream) {
    const float* x    = (const float*)d_in[0];
    const float* W0   = (const float*)d_in[1];
    const float* bn0s = (const float*)d_in[2];
    const float* bn0b = (const float*)d_in[3];
    const float* W1   = (const float*)d_in[4];
    const float* bn1s = (const float*)d_in[5];
    const float* bn1b = (const float*)d_in[6];
    const float* Wc   = (const float*)d_in[7];
    const float* bncs = (const float*)d_in[8];
    const float* bncb = (const float*)d_in[9];

    _Float16* w1f = (_Float16*)d_ws;             // 24576 f16 = 48 KiB
    int* idx = (int*)((char*)d_ws + 65536);      // 16384*20 ints = 1.25 MiB

    prep_w1f<<<96, 256, 0, stream>>>(W1, w1f);
    topk_kernel<<<4096, 256, 0, stream>>>(x, idx);
    mlp_mfma<<<2048, 128, 0, stream>>>(x, idx, W0, bn0s, bn0b, w1f,
                                       bn1s, bn1b, Wc, bncs, bncb,
                                       (float*)d_out);
}

// Round 4
// 196.899 us; speedup vs baseline: 4.0854x; 1.1672x over previous
//
#include <hip/hip_runtime.h>

#define NEGSLOPE 0.2f
#define NINF (-3.4e38f)

typedef _Float16 half8 __attribute__((ext_vector_type(8)));
typedef float f32x4 __attribute__((ext_vector_type(4)));

#define YSTRIDE 72  // f16 units, padded from 64 to break bank alignment

// ---------------------------------------------------------------------------
// prep: W1 (384,64) row-major -> B-fragment order for the K=384 fused GEMM.
// Fragment (ks<12, t4<4): lane L (q=L>>4, c=L&15) holds 8 f16:
//   B[kbig = 32ks + 8q + j][u = 16t4 + c],  kbig = i*64 + o  (i=ks>>1,
//   o=32(ks&1)+8q+j),  B[i*64+o][u] = W1[u*6+i][o]
// ---------------------------------------------------------------------------
__global__ void prep_w1g(const float* __restrict__ w1, _Float16* __restrict__ w1g) {
    int tid = blockIdx.x * 256 + threadIdx.x;
    if (tid < 24576) {
        int j = tid & 7;
        int L = (tid >> 3) & 63;
        int r = tid >> 9;          // r = ks*4 + t4
        int t4 = r & 3;
        int ks = r >> 2;
        int q = L >> 4, c = L & 15;
        int i = ks >> 1;
        int o = 32 * (ks & 1) + 8 * q + j;
        int u = 16 * t4 + c;
        w1g[tid] = (_Float16)w1[(u * 6 + i) * 64 + o];
    }
}

// ---------------------------------------------------------------------------
// topk v3: one wave per row. (key,j) packed in u64 -> single v_cmp_gt_u64
// per compare-update. Zap = in-place skh[T]=0 under a wave-uniform branch.
// Keys: sortable-uint of pd; zapped key-hi 0 can never beat a real candidate
// (real pd keys are >= ~0x00800000). Tie -> larger j (set-equivalent:
// downstream max over k is symmetric).
// ---------------------------------------------------------------------------
__device__ __forceinline__ unsigned sortkey(float f) {
    unsigned u = __float_as_uint(f);
    return u ^ ((unsigned)((int)u >> 31) | 0x80000000u);
}

template <int CTRL>
__device__ __forceinline__ unsigned long long dpp_pair(unsigned long long v) {
    int lo = (int)(unsigned)v;
    int hi = (int)(unsigned)(v >> 32);
    int olo = __builtin_amdgcn_update_dpp(0, lo, CTRL, 0xF, 0xF, false);
    int ohi = __builtin_amdgcn_update_dpp(0, hi, CTRL, 0xF, 0xF, false);
    return ((unsigned long long)(unsigned)ohi << 32) | (unsigned)olo;
}

__global__ __launch_bounds__(256) void topk_kernel(const float* __restrict__ x,
                                                   int* __restrict__ idx_out) {
    const int wave = threadIdx.x >> 6;
    const int lane = threadIdx.x & 63;
    const int row = blockIdx.x * 4 + wave;
    const int b = row >> 11;
    const int n = row & 2047;
    const float* xb = x + b * 6144;
    const float xn0 = xb[n];
    const float xn1 = xb[2048 + n];
    const float xn2 = xb[4096 + n];
    const float xxn = xn0 * xn0 + xn1 * xn1 + xn2 * xn2;

    unsigned skh[32];             // key-hi per candidate t (j = t*64+lane)
    unsigned long long g[4];      // per-group best packed (key<<32 | j)
#pragma unroll
    for (int gg = 0; gg < 4; ++gg) g[gg] = 0ull;

#pragma unroll
    for (int t = 0; t < 32; ++t) {
        const int j = t * 64 + lane;
        const float c0 = xb[j];
        const float c1 = xb[2048 + j];
        const float c2 = xb[4096 + j];
        const float dot = c0 * xn0 + c1 * xn1 + c2 * xn2;
        const float xxj = c0 * c0 + c1 * c1 + c2 * c2;
        const float p = 2.f * dot - xxn - xxj;
        const unsigned s = sortkey(p);
        skh[t] = s;
        const unsigned long long cand = ((unsigned long long)s << 32) | (unsigned)j;
        const int gi = t >> 3;
        if (cand > g[gi]) g[gi] = cand;
    }

    const int out_base = row * 20;

#define RGROUP(G)                                                              \
    {                                                                          \
        unsigned long long nb = 0ull;                                          \
        _Pragma("unroll") for (int u = 0; u < 8; ++u) {                        \
            const int T = (G) * 8 + u;                                         \
            if (T == wt) skh[T] = (lane == wl) ? 0u : skh[T];                  \
            const unsigned long long cand =                                    \
                ((unsigned long long)skh[T] << 32) | (unsigned)(T * 64 + lane);\
            if (cand > nb) nb = cand;                                          \
        }                                                                      \
        g[(G)] = nb;                                                           \
    }

    for (int k = 0; k < 20; ++k) {
        unsigned long long bp = g[0];
        if (g[1] > bp) bp = g[1];
        if (g[2] > bp) bp = g[2];
        if (g[3] > bp) bp = g[3];
        // wave max: DPP reduction, result lands in lane 63
        { unsigned long long o = dpp_pair<0x111>(bp); if (o > bp) bp = o; }  // row_shr:1
        { unsigned long long o = dpp_pair<0x112>(bp); if (o > bp) bp = o; }  // row_shr:2
        { unsigned long long o = dpp_pair<0x114>(bp); if (o > bp) bp = o; }  // row_shr:4
        { unsigned long long o = dpp_pair<0x118>(bp); if (o > bp) bp = o; }  // row_shr:8
        { unsigned long long o = dpp_pair<0x142>(bp); if (o > bp) bp = o; }  // row_bcast:15
        { unsigned long long o = dpp_pair<0x143>(bp); if (o > bp) bp = o; }  // row_bcast:31
        const int bj = __builtin_amdgcn_readlane((int)(unsigned)bp, 63);
        if (lane == 0) idx_out[out_base + k] = bj;

        if (k < 19) {
            const int wt = bj >> 6;
            const int wl = bj & 63;
            const int wg = bj >> 9;
            switch (wg) {
                case 0: RGROUP(0) break;
                case 1: RGROUP(1) break;
                case 2: RGROUP(2) break;
                default: RGROUP(3) break;
            }
        }
    }
#undef RGROUP
}

// ---------------------------------------------------------------------------
// mlp via single K=384 MFMA GEMM: out[edge][u] = sum_{k=i*64+o} (y_o * e_i)
// * W1''[k][u].  A = y (x) e built on the fly: Anew[m] = e_i(f16 splat) *
// y-frag[m][ks&1] (4 v_pk_mul_f16).  acc chains through MFMA C across all
// 12 k-steps (no per-tile C init, no f32 epilogue FMA in loop).
// ks-loop NOT unrolled (i6 over 6, 2 ks inside) -> only 32 B-regs live,
// no VGPR spill.
// ---------------------------------------------------------------------------
__global__ __launch_bounds__(128) void mlp_mfma(
    const float* __restrict__ x, const int* __restrict__ idx,
    const float* __restrict__ w0, const float* __restrict__ bn0s,
    const float* __restrict__ bn0b, const _Float16* __restrict__ w1g,
    const float* __restrict__ bn1s, const float* __restrict__ bn1b,
    const float* __restrict__ wc, const float* __restrict__ bncs,
    const float* __restrict__ bncb, float* __restrict__ out) {
    __shared__ __align__(16) _Float16 yL[2][80 * YSTRIDE];
    __shared__ __align__(4) _Float16 ehL[2][6][80];
    const int wave = threadIdx.x >> 6;
    const int lane = threadIdx.x & 63;
    const int q = lane >> 4, c = lane & 15;
    const int gw = blockIdx.x * 2 + wave;     // 0..4095
    const int b = gw >> 9;                    // 512 waves per batch
    const int P0 = (gw & 511) * 4;
    const float* xb = x + b * 6144;
    _Float16* yw = yL[wave];
    _Float16(*ehw)[80] = ehL[wave];

    // ---- e-stage: lane <-> edge_local (and +64 for lanes<16) ----
    float e0[6], e1_[6];
    {
        const int k = lane >> 2, pt = lane & 3;
        const int n = P0 + pt;
        const int j = idx[(b * 2048 + n) * 20 + k];
        const float c0 = xb[n], c1 = xb[2048 + n], c2 = xb[4096 + n];
        e0[0] = xb[j] - c0; e0[1] = xb[2048 + j] - c1; e0[2] = xb[4096 + j] - c2;
        e0[3] = c0; e0[4] = c1; e0[5] = c2;
#pragma unroll
        for (int i = 0; i < 6; ++i) ehw[i][lane] = (_Float16)e0[i];
    }
#pragma unroll
    for (int i = 0; i < 6; ++i) e1_[i] = 0.f;
    if (lane < 16) {
        const int el = 64 + lane;
        const int k = el >> 2, pt = el & 3;
        const int n = P0 + pt;
        const int j = idx[(b * 2048 + n) * 20 + k];
        const float c0 = xb[n], c1 = xb[2048 + n], c2 = xb[4096 + n];
        e1_[0] = xb[j] - c0; e1_[1] = xb[2048 + j] - c1; e1_[2] = xb[4096 + j] - c2;
        e1_[3] = c0; e1_[4] = c1; e1_[5] = c2;
#pragma unroll
        for (int i = 0; i < 6; ++i) ehw[i][el] = (_Float16)e1_[i];
    }

    // ---- y-stage: lane = edge, loop o; W0/bn0 wave-uniform scalars ----
#pragma unroll 8
    for (int o = 0; o < 64; ++o) {
        const float s0 = bn0s[o], b0 = bn0b[o];
        const float* wr = w0 + o * 6;
        float y = wr[0] * e0[0] + wr[1] * e0[1] + wr[2] * e0[2] +
                  wr[3] * e0[3] + wr[4] * e0[4] + wr[5] * e0[5];
        y = y * s0 + b0;
        y = fmaxf(y, NEGSLOPE * y);
        yw[lane * YSTRIDE + o] = (_Float16)y;
        if (lane < 16) {
            float y2 = wr[0] * e1_[0] + wr[1] * e1_[1] + wr[2] * e1_[2] +
                       wr[3] * e1_[3] + wr[4] * e1_[4] + wr[5] * e1_[5];
            y2 = y2 * s0 + b0;
            y2 = fmaxf(y2, NEGSLOPE * y2);
            yw[(64 + lane) * YSTRIDE + o] = (_Float16)y2;
        }
    }

    __syncthreads();

    // ---- y-fragments: A_[m][h] = y[edge=16m+c][o = 32h+8q .. +7] ----
    half8 A_[5][2];
#pragma unroll
    for (int m = 0; m < 5; ++m)
#pragma unroll
        for (int h = 0; h < 2; ++h)
            A_[m][h] = *(const half8*)&yw[(16 * m + c) * YSTRIDE + 32 * h + 8 * q];

    const half8* w1g8 = (const half8*)w1g;

    f32x4 acc[5][4];  // [m][t4], u = 16*t4 + c, edge row = 4q + r
#pragma unroll
    for (int m = 0; m < 5; ++m)
#pragma unroll
        for (int t4 = 0; t4 < 4; ++t4) acc[m][t4] = (f32x4){0.f, 0.f, 0.f, 0.f};

    // ---- main loop: 12 k-steps as 6 x 2, B live only within ks ----
#pragma unroll 1
    for (int i6 = 0; i6 < 6; ++i6) {
        _Float16 es[5];
#pragma unroll
        for (int m = 0; m < 5; ++m) es[m] = ehw[i6][16 * m + c];
#pragma unroll
        for (int ks2 = 0; ks2 < 2; ++ks2) {
            const int ks = 2 * i6 + ks2;
            half8 B[4];
#pragma unroll
            for (int t4 = 0; t4 < 4; ++t4)
                B[t4] = w1g8[(ks * 4 + t4) * 64 + lane];
#pragma unroll
            for (int m = 0; m < 5; ++m) {
                half8 An = A_[m][ks2] * es[m];
#pragma unroll
                for (int t4 = 0; t4 < 4; ++t4)
                    acc[m][t4] = __builtin_amdgcn_mfma_f32_16x16x32_f16(
                        An, B[t4], acc[m][t4], 0, 0, 0);
            }
        }
    }

    // ---- bn1 + leaky + max over k (k = 4m+q) ----
    float bs1[4], bb1[4];
#pragma unroll
    for (int t4 = 0; t4 < 4; ++t4) {
        bs1[t4] = bn1s[16 * t4 + c];
        bb1[t4] = bn1b[16 * t4 + c];
    }

    float x1[4][4];  // [pt r][t4]
#pragma unroll
    for (int r = 0; r < 4; ++r)
#pragma unroll
        for (int t4 = 0; t4 < 4; ++t4) {
            float v = NINF;
#pragma unroll
            for (int m = 0; m < 5; ++m) {
                float w = acc[m][t4][r] * bs1[t4] + bb1[t4];
                w = fmaxf(w, NEGSLOPE * w);
                v = fmaxf(v, w);
            }
            v = fmaxf(v, __shfl_xor(v, 16, 64));
            v = fmaxf(v, __shfl_xor(v, 32, 64));
            x1[r][t4] = v;
        }

    // ---- head: z[pt][co] = leaky(bnc(sum_u x1*wc)) ----
    float wcv[3][4];
#pragma unroll
    for (int co = 0; co < 3; ++co)
#pragma unroll
        for (int t4 = 0; t4 < 4; ++t4) wcv[co][t4] = wc[co * 64 + 16 * t4 + c];

    float part[4][3];
#pragma unroll
    for (int r = 0; r < 4; ++r)
#pragma unroll
        for (int co = 0; co < 3; ++co) {
            float s = x1[r][0] * wcv[co][0] + x1[r][1] * wcv[co][1] +
                      x1[r][2] * wcv[co][2] + x1[r][3] * wcv[co][3];
#pragma unroll
            for (int d = 1; d < 16; d <<= 1) s += __shfl_xor(s, d, 64);
            part[r][co] = s;
        }

    if (c == 0 && q < 3) {
        const float sc = bncs[q], bc = bncb[q];
#pragma unroll
        for (int r = 0; r < 4; ++r) {
            float z = part[r][q] * sc + bc;
            z = fmaxf(z, NEGSLOPE * z);
            out[(b * 3 + q) * 2048 + P0 + r] = z;
        }
    }
}

// ---------------------------------------------------------------------------
extern "C" void kernel_launch(void* const* d_in, const int* in_sizes, int n_in,
                              void* d_out, int out_size, void* d_ws, size_t ws_size,
                              hipStream_t stream) {
    const float* x    = (const float*)d_in[0];
    const float* W0   = (const float*)d_in[1];
    const float* bn0s = (const float*)d_in[2];
    const float* bn0b = (const float*)d_in[3];
    const float* W1   = (const float*)d_in[4];
    const float* bn1s = (const float*)d_in[5];
    const float* bn1b = (const float*)d_in[6];
    const float* Wc   = (const float*)d_in[7];
    const float* bncs = (const float*)d_in[8];
    const float* bncb = (const float*)d_in[9];

    _Float16* w1g = (_Float16*)d_ws;             // 24576 f16 = 48 KiB
    int* idx = (int*)((char*)d_ws + 65536);      // 16384*20 ints = 1.25 MiB

    prep_w1g<<<96, 256, 0, stream>>>(W1, w1g);
    topk_kernel<<<4096, 256, 0, stream>>>(x, idx);
    mlp_mfma<<<2048, 128, 0, stream>>>(x, idx, W0, bn0s, bn0b, w1g,
                                       bn1s, bn1b, Wc, bncs, bncb,
                                       (float*)d_out);
}

// Round 5
// 173.393 us; speedup vs baseline: 4.6392x; 1.1356x over previous
//
#include <hip/hip_runtime.h>

#define NEGSLOPE 0.2f
#define NINF (-3.4e38f)

typedef _Float16 half8 __attribute__((ext_vector_type(8)));
typedef float f32x4 __attribute__((ext_vector_type(4)));

#define YSTRIDE 72  // f16 units, padded from 64 to break bank alignment

// ---------------------------------------------------------------------------
// prep: W1 (384,64) row-major -> B-fragment order for the K=384 fused GEMM.
// (unchanged, known-correct)
// ---------------------------------------------------------------------------
__global__ void prep_w1g(const float* __restrict__ w1, _Float16* __restrict__ w1g) {
    int tid = blockIdx.x * 256 + threadIdx.x;
    if (tid < 24576) {
        int j = tid & 7;
        int L = (tid >> 3) & 63;
        int r = tid >> 9;          // r = ks*4 + t4
        int t4 = r & 3;
        int ks = r >> 2;
        int q = L >> 4, c = L & 15;
        int i = ks >> 1;
        int o = 32 * (ks & 1) + 8 * q + j;
        int u = 16 * t4 + c;
        w1g[tid] = (_Float16)w1[(u * 6 + i) * 64 + o];
    }
}

// ---------------------------------------------------------------------------
// topk v4: key = ~bits(||xj-xn||^2)  (squared distance >= 0, so its float
// bit-pattern IS its uint order; complement -> descending max-select; the
// self point d=0 -> key 0xFFFFFFFF is the guaranteed top-1, matching jax
// where pd[self]=0 is the max). Per-(lane,group) TOP-2 cache (u64 packed
// (key<<32)|~j) -> per-extraction "recompute" is a 4-cndmask demote; rare
// bucket-depletion refills from retained skh[32]+zmask under a wave-uniform
// branch. Wave argmax = 32-bit v_max_u32 DPP chain + ballot/ffs/readlane
// decode. Ties: winner is defined as first-ballot-lane's lane-best; only
// that lane zaps -> no duplicates, no loss (set-exact; downstream max over
// k is order-invariant).
// ---------------------------------------------------------------------------
template <int CTRL>
__device__ __forceinline__ unsigned dpp_mov(unsigned v) {
    return (unsigned)__builtin_amdgcn_update_dpp(0, (int)v, CTRL, 0xF, 0xF, false);
}

__global__ __launch_bounds__(256) void topk_kernel(const float* __restrict__ x,
                                                   int* __restrict__ idx_out) {
    const int wave = threadIdx.x >> 6;
    const int lane = threadIdx.x & 63;
    const int row = blockIdx.x * 4 + wave;
    const int b = row >> 11;
    const int n = row & 2047;
    const float* xb = x + b * 6144;
    const float xn0 = xb[n];
    const float xn1 = xb[2048 + n];
    const float xn2 = xb[4096 + n];

    unsigned skh[32];                  // key per candidate t (j = t*64+lane)
    unsigned long long g1[4], g2[4];   // per-group top-2, packed (key<<32)|~j
#pragma unroll
    for (int gg = 0; gg < 4; ++gg) { g1[gg] = 0ull; g2[gg] = 0ull; }

#pragma unroll
    for (int t = 0; t < 32; ++t) {
        const int j = t * 64 + lane;
        const float dx = xb[j] - xn0;
        const float dy = xb[2048 + j] - xn1;
        const float dz = xb[4096 + j] - xn2;
        const float d = dx * dx + dy * dy + dz * dz;
        const unsigned s = ~__float_as_uint(d);
        skh[t] = s;
        const unsigned long long cand =
            ((unsigned long long)s << 32) | (unsigned)(~j);
        const int gi = t >> 3;
        const bool c1 = cand > g1[gi];
        const unsigned long long t2 = c1 ? g1[gi] : cand;
        g1[gi] = c1 ? cand : g1[gi];
        if (t2 > g2[gi]) g2[gi] = t2;
    }

    unsigned zmask = 0u;
    const int out_base = row * 20;

#define REFILL(G)                                                              \
    {                                                                          \
        unsigned long long n1 = 0ull, n2 = 0ull;                               \
        _Pragma("unroll") for (int u = 0; u < 8; ++u) {                        \
            const int T = (G) * 8 + u;                                         \
            const unsigned sv = ((zmask >> T) & 1u) ? 0u : skh[T];             \
            const unsigned long long cc =                                      \
                ((unsigned long long)sv << 32) | (unsigned)(~(T * 64 + lane)); \
            const bool c1 = cc > n1;                                           \
            const unsigned long long tt = c1 ? n1 : cc;                        \
            n1 = c1 ? cc : n1;                                                 \
            if (tt > n2) n2 = tt;                                              \
        }                                                                      \
        g1[(G)] = n1;                                                          \
        g2[(G)] = n2;                                                          \
    }

    for (int k = 0; k < 20; ++k) {
        // lane-best over the 4 group tops (+ remember which group)
        unsigned long long lb = g1[0];
        int gb = 0;
#pragma unroll
        for (int gg = 1; gg < 4; ++gg) {
            if (g1[gg] > lb) { lb = g1[gg]; gb = gg; }
        }
        // 32-bit wave max of the key via DPP; lands in lane 63
        unsigned m = (unsigned)(lb >> 32);
        { unsigned o = dpp_mov<0x111>(m); m = o > m ? o : m; }  // row_shr:1
        { unsigned o = dpp_mov<0x112>(m); m = o > m ? o : m; }  // row_shr:2
        { unsigned o = dpp_mov<0x114>(m); m = o > m ? o : m; }  // row_shr:4
        { unsigned o = dpp_mov<0x118>(m); m = o > m ? o : m; }  // row_shr:8
        { unsigned o = dpp_mov<0x142>(m); m = o > m ? o : m; }  // row_bcast:15
        { unsigned o = dpp_mov<0x143>(m); m = o > m ? o : m; }  // row_bcast:31
        const unsigned K = (unsigned)__builtin_amdgcn_readlane((int)m, 63);
        const unsigned long long ball = __ballot((unsigned)(lb >> 32) == K);
        const int Ls = __ffsll((unsigned long long)ball) - 1;
        const unsigned lo =
            (unsigned)__builtin_amdgcn_readlane((int)(unsigned)lb, Ls);
        const int bj = (int)~lo;  // winning candidate index (wave-uniform)
        if (lane == 0) idx_out[out_base + k] = bj;

        if (k < 19) {
            const int gstar = __builtin_amdgcn_readlane(gb, Ls);  // uniform
            const bool isL = (lane == Ls);
            const int tstar = bj >> 6;  // uniform
            zmask |= isL ? (1u << tstar) : 0u;
            unsigned h1;
            switch (gstar) {
                case 0:
                    if (isL) { g1[0] = g2[0]; g2[0] = 0ull; }
                    h1 = (unsigned)(g1[0] >> 32); break;
                case 1:
                    if (isL) { g1[1] = g2[1]; g2[1] = 0ull; }
                    h1 = (unsigned)(g1[1] >> 32); break;
                case 2:
                    if (isL) { g1[2] = g2[2]; g2[2] = 0ull; }
                    h1 = (unsigned)(g1[2] >> 32); break;
                default:
                    if (isL) { g1[3] = g2[3]; g2[3] = 0ull; }
                    h1 = (unsigned)(g1[3] >> 32); break;
            }
            // rare: winner's bucket depleted -> rebuild its top-2 (idempotent
            // for non-winner lanes; wave-uniform branch)
            if (__builtin_amdgcn_readlane((int)h1, Ls) == 0) {
                switch (gstar) {
                    case 0: REFILL(0) break;
                    case 1: REFILL(1) break;
                    case 2: REFILL(2) break;
                    default: REFILL(3) break;
                }
            }
        }
    }
#undef REFILL
}

// ---------------------------------------------------------------------------
// mlp via single K=384 MFMA GEMM. Changes vs R4: A-fragments re-read from
// LDS inside the k-loop (frees ~40 VGPRs; suspicion: R4 spilled), and
// __launch_bounds__(128,2) caps the allocator at 256 VGPR / >=2 waves/SIMD.
// ---------------------------------------------------------------------------
__global__ __launch_bounds__(128, 2) void mlp_mfma(
    const float* __restrict__ x, const int* __restrict__ idx,
    const float* __restrict__ w0, const float* __restrict__ bn0s,
    const float* __restrict__ bn0b, const _Float16* __restrict__ w1g,
    const float* __restrict__ bn1s, const float* __restrict__ bn1b,
    const float* __restrict__ wc, const float* __restrict__ bncs,
    const float* __restrict__ bncb, float* __restrict__ out) {
    __shared__ __align__(16) _Float16 yL[2][80 * YSTRIDE];
    __shared__ __align__(4) _Float16 ehL[2][6][80];
    const int wave = threadIdx.x >> 6;
    const int lane = threadIdx.x & 63;
    const int q = lane >> 4, c = lane & 15;
    const int gw = blockIdx.x * 2 + wave;     // 0..4095
    const int b = gw >> 9;                    // 512 waves per batch
    const int P0 = (gw & 511) * 4;
    const float* xb = x + b * 6144;
    _Float16* yw = yL[wave];
    _Float16(*ehw)[80] = ehL[wave];

    // ---- e-stage: lane <-> edge_local (and +64 for lanes<16) ----
    float e0[6], e1_[6];
    {
        const int k = lane >> 2, pt = lane & 3;
        const int n = P0 + pt;
        const int j = idx[(b * 2048 + n) * 20 + k];
        const float c0 = xb[n], c1 = xb[2048 + n], c2 = xb[4096 + n];
        e0[0] = xb[j] - c0; e0[1] = xb[2048 + j] - c1; e0[2] = xb[4096 + j] - c2;
        e0[3] = c0; e0[4] = c1; e0[5] = c2;
#pragma unroll
        for (int i = 0; i < 6; ++i) ehw[i][lane] = (_Float16)e0[i];
    }
#pragma unroll
    for (int i = 0; i < 6; ++i) e1_[i] = 0.f;
    if (lane < 16) {
        const int el = 64 + lane;
        const int k = el >> 2, pt = el & 3;
        const int n = P0 + pt;
        const int j = idx[(b * 2048 + n) * 20 + k];
        const float c0 = xb[n], c1 = xb[2048 + n], c2 = xb[4096 + n];
        e1_[0] = xb[j] - c0; e1_[1] = xb[2048 + j] - c1; e1_[2] = xb[4096 + j] - c2;
        e1_[3] = c0; e1_[4] = c1; e1_[5] = c2;
#pragma unroll
        for (int i = 0; i < 6; ++i) ehw[i][el] = (_Float16)e1_[i];
    }

    // ---- y-stage: lane = edge, loop o; W0/bn0 wave-uniform scalars ----
#pragma unroll 8
    for (int o = 0; o < 64; ++o) {
        const float s0 = bn0s[o], b0 = bn0b[o];
        const float* wr = w0 + o * 6;
        float y = wr[0] * e0[0] + wr[1] * e0[1] + wr[2] * e0[2] +
                  wr[3] * e0[3] + wr[4] * e0[4] + wr[5] * e0[5];
        y = y * s0 + b0;
        y = fmaxf(y, NEGSLOPE * y);
        yw[lane * YSTRIDE + o] = (_Float16)y;
        if (lane < 16) {
            float y2 = wr[0] * e1_[0] + wr[1] * e1_[1] + wr[2] * e1_[2] +
                       wr[3] * e1_[3] + wr[4] * e1_[4] + wr[5] * e1_[5];
            y2 = y2 * s0 + b0;
            y2 = fmaxf(y2, NEGSLOPE * y2);
            yw[(64 + lane) * YSTRIDE + o] = (_Float16)y2;
        }
    }

    __syncthreads();

    const half8* w1g8 = (const half8*)w1g;

    f32x4 acc[5][4];  // [m][t4], u = 16*t4 + c, edge row = 4q + r
#pragma unroll
    for (int m = 0; m < 5; ++m)
#pragma unroll
        for (int t4 = 0; t4 < 4; ++t4) acc[m][t4] = (f32x4){0.f, 0.f, 0.f, 0.f};

    // ---- main loop: 12 k-steps as 6 x 2; A re-read from LDS each step ----
#pragma unroll 1
    for (int i6 = 0; i6 < 6; ++i6) {
        _Float16 es[5];
#pragma unroll
        for (int m = 0; m < 5; ++m) es[m] = ehw[i6][16 * m + c];
#pragma unroll
        for (int ks2 = 0; ks2 < 2; ++ks2) {
            const int ks = 2 * i6 + ks2;
            half8 B[4];
#pragma unroll
            for (int t4 = 0; t4 < 4; ++t4)
                B[t4] = w1g8[(ks * 4 + t4) * 64 + lane];
#pragma unroll
            for (int m = 0; m < 5; ++m) {
                const half8 Af =
                    *(const half8*)&yw[(16 * m + c) * YSTRIDE + 32 * ks2 + 8 * q];
                const half8 An = Af * es[m];
#pragma unroll
                for (int t4 = 0; t4 < 4; ++t4)
                    acc[m][t4] = __builtin_amdgcn_mfma_f32_16x16x32_f16(
                        An, B[t4], acc[m][t4], 0, 0, 0);
            }
        }
    }

    // ---- bn1 + leaky + max over k (k = 4m+q) ----
    float bs1[4], bb1[4];
#pragma unroll
    for (int t4 = 0; t4 < 4; ++t4) {
        bs1[t4] = bn1s[16 * t4 + c];
        bb1[t4] = bn1b[16 * t4 + c];
    }

    float x1[4][4];  // [pt r][t4]
#pragma unroll
    for (int r = 0; r < 4; ++r)
#pragma unroll
        for (int t4 = 0; t4 < 4; ++t4) {
            float v = NINF;
#pragma unroll
            for (int m = 0; m < 5; ++m) {
                float w = acc[m][t4][r] * bs1[t4] + bb1[t4];
                w = fmaxf(w, NEGSLOPE * w);
                v = fmaxf(v, w);
            }
            v = fmaxf(v, __shfl_xor(v, 16, 64));
            v = fmaxf(v, __shfl_xor(v, 32, 64));
            x1[r][t4] = v;
        }

    // ---- head: z[pt][co] = leaky(bnc(sum_u x1*wc)) ----
    float wcv[3][4];
#pragma unroll
    for (int co = 0; co < 3; ++co)
#pragma unroll
        for (int t4 = 0; t4 < 4; ++t4) wcv[co][t4] = wc[co * 64 + 16 * t4 + c];

    float part[4][3];
#pragma unroll
    for (int r = 0; r < 4; ++r)
#pragma unroll
        for (int co = 0; co < 3; ++co) {
            float s = x1[r][0] * wcv[co][0] + x1[r][1] * wcv[co][1] +
                      x1[r][2] * wcv[co][2] + x1[r][3] * wcv[co][3];
#pragma unroll
            for (int d = 1; d < 16; d <<= 1) s += __shfl_xor(s, d, 64);
            part[r][co] = s;
        }

    if (c == 0 && q < 3) {
        const float sc = bncs[q], bc = bncb[q];
#pragma unroll
        for (int r = 0; r < 4; ++r) {
            float z = part[r][q] * sc + bc;
            z = fmaxf(z, NEGSLOPE * z);
            out[(b * 3 + q) * 2048 + P0 + r] = z;
        }
    }
}

// ---------------------------------------------------------------------------
extern "C" void kernel_launch(void* const* d_in, const int* in_sizes, int n_in,
                              void* d_out, int out_size, void* d_ws, size_t ws_size,
                              hipStream_t stream) {
    const float* x    = (const float*)d_in[0];
    const float* W0   = (const float*)d_in[1];
    const float* bn0s = (const float*)d_in[2];
    const float* bn0b = (const float*)d_in[3];
    const float* W1   = (const float*)d_in[4];
    const float* bn1s = (const float*)d_in[5];
    const float* bn1b = (const float*)d_in[6];
    const float* Wc   = (const float*)d_in[7];
    const float* bncs = (const float*)d_in[8];
    const float* bncb = (const float*)d_in[9];

    _Float16* w1g = (_Float16*)d_ws;             // 24576 f16 = 48 KiB
    int* idx = (int*)((char*)d_ws + 65536);      // 16384*20 ints = 1.25 MiB

    prep_w1g<<<96, 256, 0, stream>>>(W1, w1g);
    topk_kernel<<<4096, 256, 0, stream>>>(x, idx);
    mlp_mfma<<<2048, 128, 0, stream>>>(x, idx, W0, bn0s, bn0b, w1g,
                                       bn1s, bn1b, Wc, bncs, bncb,
                                       (float*)d_out);
}